// Round 1
// 1651.367 us; speedup vs baseline: 1.1556x; 1.1556x over previous
//
#include <hip/hip_runtime.h>
#include <stdint.h>

// Qwen3.5 MoE block: N=4096 tokens, H=2048, E=16, K=4, I_moe=1408, I_sh=5632
// R3: (1) supertile + XCD-chunked block swizzle on all GEMMs: 8 consecutive
// same-XCD blocks share one B-tile, per-group A set (4 MB) fits one XCD L2.
// Active-mtile count computed in-kernel from counts (m204 bijective mapping
// keeps routed work balanced across XCDs). (2) BK 32->64: half the barrier
// drains, 32 MFMA/wave/iter. XOR chunk swizzle p = l ^ (row&7) for the
// 128 B row stride (2-way banks = free).

#define N_TOK 4096
#define H_DIM 2048
#define E_NUM 16
#define TOPK  4
#define IMOE  1408
#define ISH   5632
#define SLOTS (N_TOK*TOPK)       // 16384

#define MT 128
#define BK 64                     // bf16 elems along k per tile (128 B, 8 chunks)

typedef __attribute__((ext_vector_type(8))) short bf16x8;   // 8 bf16 = 4 VGPRs
typedef __attribute__((ext_vector_type(4))) float f32x4;

static __device__ inline unsigned short f2bf(float f) {
    union { float f; unsigned u; } v; v.f = f;
    unsigned r = v.u + 0x7fffu + ((v.u >> 16) & 1u);   // RNE
    return (unsigned short)(r >> 16);
}

// async global->LDS, 16 bytes per lane. LDS dest = wave-uniform base + lane*16.
static __device__ inline void glds16(const unsigned short* g, unsigned short* l) {
    __builtin_amdgcn_global_load_lds(
        (const __attribute__((address_space(1))) void*)g,
        (__attribute__((address_space(3))) void*)l, 16, 0, 0);
}

// Block-id decode: flat (per-z) id -> (ntile, mtile).
// Step 1: bijective XCD chunking (m204): XCD x = f&7 owns a contiguous chunk
//         of the logical sequence -> consecutive logicals stay on one XCD L2.
// Step 2: supertile order: groups of GM=8 mtiles; within a group mtile varies
//         fastest -> 8 consecutive logicals share one B-tile (ntile).
static __device__ inline bool decode_tile(int bx, int by, int NX, int NYact,
                                          int& nt, int& mt) {
    int f = by * NX + bx;
    int NB = NX * NYact;
    if (f >= NB) return false;
    int q = NB >> 3, rr = NB & 7;
    int x = f & 7, s = f >> 3;
    int L = (x < rr ? x * (q + 1) : rr * (q + 1) + (x - rr) * q) + s;
    const int GM = 8;
    int G = GM * NX;
    int g = L / G, r2 = L - g * G;
    int gm = NYact - g * GM; if (gm > GM) gm = GM;
    nt = r2 / gm;
    mt = g * GM + (r2 - nt * gm);
    return true;
}

// ---------------- fp32 -> bf16 (no transpose), for hidden_states ----------------
__global__ void cvt_h_kernel(const float* __restrict__ in, unsigned short* __restrict__ out, int n4) {
    int i = blockIdx.x * blockDim.x + threadIdx.x;
    if (i < n4) {
        float4 v = *(const float4*)(in + (size_t)i * 4);
        ushort4 o; o.x = f2bf(v.x); o.y = f2bf(v.y); o.z = f2bf(v.z); o.w = f2bf(v.w);
        *(ushort4*)(out + (size_t)i * 4) = o;
    }
}

// ---------------- fp32 [R,C] -> bf16 [C,R] (per z-slice) ----------------
__global__ void transpose_cvt_kernel(const float* __restrict__ in, unsigned short* __restrict__ out,
                                     int R, int C) {
    __shared__ float tile[32][33];
    const float* ip = in + (size_t)blockIdx.z * R * C;
    unsigned short* op = out + (size_t)blockIdx.z * R * C;
    int cb = blockIdx.x * 32, rb = blockIdx.y * 32;
    int tx = threadIdx.x, ty = threadIdx.y;            // (32, 8)
    for (int i = 0; i < 4; i++)
        tile[ty + i * 8][tx] = ip[(size_t)(rb + ty + i * 8) * C + cb + tx];
    __syncthreads();
    for (int i = 0; i < 4; i++)
        op[(size_t)(cb + ty + i * 8) * R + rb + tx] = f2bf(tile[tx][ty + i * 8]);
}

// ---------------- router: fp32 logits -> softmax -> top4 -> renorm; + sigmoid gate ----------------
__global__ __launch_bounds__(256) void router_kernel(
    const float* __restrict__ h, const float* __restrict__ rw, const float* __restrict__ gw,
    int* __restrict__ topk_idx, float* __restrict__ topk_w,
    float* __restrict__ sg, int* __restrict__ counts) {
    int n = blockIdx.x;
    const float* hp = h + (size_t)n * H_DIM;
    int t = threadIdx.x;
    int e = t >> 4, part = t & 15;
    const float* rp = rw + (size_t)e * H_DIM;
    float acc = 0.f;
    for (int j = part; j < H_DIM; j += 16) acc += hp[j] * rp[j];
    for (int d = 8; d; d >>= 1) acc += __shfl_down(acc, d, 16);
    __shared__ float logits[E_NUM];
    if (part == 0) logits[e] = acc;
    float sacc = 0.f;
    for (int j = t; j < H_DIM; j += 256) sacc += hp[j] * gw[j];
    __shared__ float sred[256];
    sred[t] = sacc;
    __syncthreads();
    for (int d = 128; d; d >>= 1) { if (t < d) sred[t] += sred[t + d]; __syncthreads(); }
    if (t == 0) {
        float m = logits[0];
        for (int i = 1; i < E_NUM; i++) m = fmaxf(m, logits[i]);
        float p[E_NUM]; float s = 0.f;
        for (int i = 0; i < E_NUM; i++) { p[i] = expf(logits[i] - m); s += p[i]; }
        float invs = 1.f / s;
        for (int i = 0; i < E_NUM; i++) p[i] *= invs;
        int idx[TOPK]; float val[TOPK]; float vs = 0.f;
        for (int k = 0; k < TOPK; k++) {
            int bi = 0; float bv = -1.f;
            for (int i = 0; i < E_NUM; i++) if (p[i] > bv) { bv = p[i]; bi = i; }
            idx[k] = bi; val[k] = bv; vs += bv; p[bi] = -2.f;
        }
        float inv = 1.f / fmaxf(vs, 1e-9f);
        for (int k = 0; k < TOPK; k++) {
            topk_idx[n * TOPK + k] = idx[k];
            topk_w[n * TOPK + k] = val[k] * inv;
            atomicAdd(&counts[idx[k]], 1);
        }
        sg[n] = 1.f / (1.f + expf(-sred[0]));
    }
}

// ---------------- exclusive scan of 16 counts (tiny) ----------------
__global__ void scan_kernel(const int* __restrict__ counts, int* __restrict__ offsets,
                            int* __restrict__ cursor) {
    int s = 0;
    for (int e = 0; e < E_NUM; e++) { offsets[e] = s; cursor[e] = s; s += counts[e]; }
}

// ---------------- scatter token->slot ----------------
__global__ void bucketize_kernel(const int* __restrict__ topk_idx, const float* __restrict__ topk_w,
                                 int* __restrict__ cursor, int* __restrict__ slot_tok,
                                 float* __restrict__ slot_w) {
    int n = blockIdx.x * blockDim.x + threadIdx.x;
    if (n >= N_TOK) return;
    for (int k = 0; k < TOPK; k++) {
        int e = topk_idx[n * TOPK + k];
        int s = atomicAdd(&cursor[e], 1);
        slot_tok[s] = n;
        slot_w[s] = topk_w[n * TOPK + k];
    }
}

// ---------------- gather bf16 token rows into slot order ----------------
__global__ __launch_bounds__(256) void gather_kernel(const unsigned short* __restrict__ hbf,
                                                     const int* __restrict__ slot_tok,
                                                     unsigned short* __restrict__ A) {
    int s = blockIdx.x;
    int tok = slot_tok[s];
    const uint4* src = (const uint4*)(hbf + (size_t)tok * H_DIM);
    uint4* dst = (uint4*)(A + (size_t)s * H_DIM);
    dst[threadIdx.x] = src[threadIdx.x];
}

// ---------------- fused gate/up GEMM + SiLU*mul -> bf16 act ----------------
// Block tile: 128 rows x 64 cols, dual accumulators (gate & up share A-frags).
// Per wave (2x2 grid): 64x32, accg[4][2]+accu[4][2] = 64 AGPR.
// BK=64: per thread 8x glds16/iter; XOR chunk swizzle p = l ^ (row&7).
__global__ __launch_bounds__(256, 2) void gemm_dual_kernel(
    const unsigned short* __restrict__ A, const unsigned short* __restrict__ Bg,
    const unsigned short* __restrict__ Bu, unsigned short* __restrict__ act,
    const int* __restrict__ counts, const int* __restrict__ offsets,
    int K, int N, int fixedM) {
    int e = blockIdx.z;
    int c, off;
    if (counts) { c = counts[e]; off = offsets[e]; } else { c = fixedM; off = 0; }
    int NYact = (c + MT - 1) / MT;
    int nt, mt;
    if (!decode_tile(blockIdx.x, blockIdx.y, gridDim.x, NYact, nt, mt)) return;

    const unsigned short* Ab = A + (size_t)off * K;
    const unsigned short* Bgb = Bg + (size_t)e * (size_t)N * K;
    const unsigned short* Bub = Bu + (size_t)e * (size_t)N * K;
    unsigned short* actb = act + (size_t)off * N;

    __shared__ __align__(16) unsigned short As[MT * BK];      // 16 KB
    __shared__ __align__(16) unsigned short Bgs[64 * BK];     // 8 KB
    __shared__ __align__(16) unsigned short Bus[64 * BK];     // 8 KB

    int t = threadIdx.x;
    int wave = t >> 6, lane = t & 63;
    int wm = wave >> 1, wn = wave & 1;
    int quad = lane >> 4, l16 = lane & 15;

    f32x4 accg[4][2], accu[4][2];
    for (int i = 0; i < 4; i++) for (int j = 0; j < 2; j++) { accg[i][j] = (f32x4)0.f; accu[i][j] = (f32x4)0.f; }

    int m0 = mt * MT, n0 = nt * 64;
    // staging slot assignments (constant across k-steps): physical chunk s
    // holds logical chunk (s&7)^(row&7) of its row.
    int rA[4], cA[4];
    for (int j = 0; j < 4; j++) { int s = t + 256 * j; rA[j] = s >> 3; cA[j] = (s & 7) ^ (rA[j] & 7); }
    int rB[2], cB[2];
    for (int j = 0; j < 2; j++) { int s = t + 256 * j; rB[j] = s >> 3; cB[j] = (s & 7) ^ (rB[j] & 7); }

    for (int kt = 0; kt < K; kt += BK) {
        __syncthreads();
        for (int j = 0; j < 4; j++)
            glds16(&Ab[(size_t)(m0 + rA[j]) * K + kt + cA[j] * 8], &As[(t + 256 * j) * 8]);
        for (int j = 0; j < 2; j++) {
            glds16(&Bgb[(size_t)(n0 + rB[j]) * K + kt + cB[j] * 8], &Bgs[(t + 256 * j) * 8]);
            glds16(&Bub[(size_t)(n0 + rB[j]) * K + kt + cB[j] * 8], &Bus[(t + 256 * j) * 8]);
        }
        __syncthreads();
#pragma unroll
        for (int ks = 0; ks < 2; ks++) {
            int lbase = (ks << 2) | quad;
            bf16x8 af[4], bgf[2], buf[2];
            for (int mi = 0; mi < 4; mi++) {
                int rowl = wm * 64 + mi * 16 + l16;
                af[mi] = *(const bf16x8*)&As[rowl * BK + ((lbase ^ (rowl & 7)) * 8)];
            }
            for (int ni = 0; ni < 2; ni++) {
                int rowl = wn * 32 + ni * 16 + l16;
                int co = (lbase ^ (rowl & 7)) * 8;
                bgf[ni] = *(const bf16x8*)&Bgs[rowl * BK + co];
                buf[ni] = *(const bf16x8*)&Bus[rowl * BK + co];
            }
            for (int mi = 0; mi < 4; mi++)
                for (int ni = 0; ni < 2; ni++) {
                    accg[mi][ni] = __builtin_amdgcn_mfma_f32_16x16x32_bf16(af[mi], bgf[ni], accg[mi][ni], 0, 0, 0);
                    accu[mi][ni] = __builtin_amdgcn_mfma_f32_16x16x32_bf16(af[mi], buf[ni], accu[mi][ni], 0, 0, 0);
                }
        }
    }
    for (int mi = 0; mi < 4; mi++) {
        for (int r = 0; r < 4; r++) {
            int rl = m0 + wm * 64 + mi * 16 + quad * 4 + r;
            if (rl < c) {
                size_t rowbase = (size_t)rl * N + n0 + wn * 32 + l16;
                for (int ni = 0; ni < 2; ni++) {
                    float g = accg[mi][ni][r];
                    float u = accu[mi][ni][r];
                    float a = (g / (1.f + __expf(-g))) * u;
                    actb[rowbase + ni * 16] = f2bf(a);
                }
            }
        }
    }
}

// ---------------- down GEMM + combine ----------------
// 128x128 tile, per wave 64x64, acc[4][4] = 64 AGPR. BK=64 + swizzle staging.
// routed: atomicAdd(out[tok,:], w_slot * y). shared: out[row,:] += sg[row] * y.
__global__ __launch_bounds__(256, 2) void gemm_down_kernel(
    const unsigned short* __restrict__ Aact, const unsigned short* __restrict__ Bd,
    float* __restrict__ out,
    const int* __restrict__ counts, const int* __restrict__ offsets,
    const int* __restrict__ slot_tok, const float* __restrict__ slot_w,
    const float* __restrict__ sg,
    int K, int N, int fixedM) {
    int e = blockIdx.z;
    bool routed = (counts != nullptr);
    int c, off;
    if (routed) { c = counts[e]; off = offsets[e]; } else { c = fixedM; off = 0; }
    int NYact = (c + MT - 1) / MT;
    int nt, mt;
    if (!decode_tile(blockIdx.x, blockIdx.y, gridDim.x, NYact, nt, mt)) return;

    const unsigned short* Ab = Aact + (size_t)off * K;
    const unsigned short* Bb = Bd + (size_t)e * (size_t)N * K;

    __shared__ __align__(16) unsigned short As[MT * BK];      // 16 KB
    __shared__ __align__(16) unsigned short Bs[MT * BK];      // 16 KB

    int t = threadIdx.x;
    int wave = t >> 6, lane = t & 63;
    int wm = wave >> 1, wn = wave & 1;
    int quad = lane >> 4, l16 = lane & 15;

    f32x4 acc[4][4];
    for (int i = 0; i < 4; i++) for (int j = 0; j < 4; j++) acc[i][j] = (f32x4)0.f;

    int m0 = mt * MT, n0 = nt * MT;
    int rA[4], cA[4];
    for (int j = 0; j < 4; j++) { int s = t + 256 * j; rA[j] = s >> 3; cA[j] = (s & 7) ^ (rA[j] & 7); }

    for (int kt = 0; kt < K; kt += BK) {
        __syncthreads();
        for (int j = 0; j < 4; j++) {
            glds16(&Ab[(size_t)(m0 + rA[j]) * K + kt + cA[j] * 8], &As[(t + 256 * j) * 8]);
            glds16(&Bb[(size_t)(n0 + rA[j]) * K + kt + cA[j] * 8], &Bs[(t + 256 * j) * 8]);
        }
        __syncthreads();
#pragma unroll
        for (int ks = 0; ks < 2; ks++) {
            int lbase = (ks << 2) | quad;
            bf16x8 af[4], bf[4];
            for (int mi = 0; mi < 4; mi++) {
                int rowl = wm * 64 + mi * 16 + l16;
                af[mi] = *(const bf16x8*)&As[rowl * BK + ((lbase ^ (rowl & 7)) * 8)];
            }
            for (int ni = 0; ni < 4; ni++) {
                int rowl = wn * 64 + ni * 16 + l16;
                bf[ni] = *(const bf16x8*)&Bs[rowl * BK + ((lbase ^ (rowl & 7)) * 8)];
            }
            for (int mi = 0; mi < 4; mi++)
                for (int ni = 0; ni < 4; ni++)
                    acc[mi][ni] = __builtin_amdgcn_mfma_f32_16x16x32_bf16(af[mi], bf[ni], acc[mi][ni], 0, 0, 0);
        }
    }
    for (int mi = 0; mi < 4; mi++) {
        for (int r = 0; r < 4; r++) {
            int rl = m0 + wm * 64 + mi * 16 + quad * 4 + r;
            if (rl < c) {
                int col = n0 + wn * 64 + l16;
                if (routed) {
                    int s = off + rl;
                    int tok = slot_tok[s];
                    float w = slot_w[s];
                    float* ob = out + (size_t)tok * N + col;
                    for (int ni = 0; ni < 4; ni++)
                        atomicAdd(ob + ni * 16, w * acc[mi][ni][r]);
                } else {
                    float w = sg[rl];
                    float* ob = out + (size_t)rl * N + col;
                    for (int ni = 0; ni < 4; ni++)
                        ob[ni * 16] += w * acc[mi][ni][r];
                }
            }
        }
    }
}

extern "C" void kernel_launch(void* const* d_in, const int* in_sizes, int n_in,
                              void* d_out, int out_size, void* d_ws, size_t ws_size,
                              hipStream_t stream) {
    const float* h   = (const float*)d_in[0];
    const float* rw  = (const float*)d_in[1];
    const float* wg  = (const float*)d_in[2];
    const float* wu  = (const float*)d_in[3];
    const float* wd  = (const float*)d_in[4];
    const float* shg = (const float*)d_in[5];
    const float* shu = (const float*)d_in[6];
    const float* shd = (const float*)d_in[7];
    const float* sgw = (const float*)d_in[8];
    float* out = (float*)d_out;

    char* ws = (char*)d_ws;
    size_t off = 0;
    auto alloc = [&](size_t b) { size_t o = off; off += (b + 255) & ~(size_t)255; return (void*)(ws + o); };

    int*   counts   = (int*)  alloc(E_NUM * 4);
    int*   offsets  = (int*)  alloc(E_NUM * 4);
    int*   cursor   = (int*)  alloc(E_NUM * 4);
    int*   topk_idx = (int*)  alloc((size_t)N_TOK * TOPK * 4);
    float* topk_w   = (float*)alloc((size_t)N_TOK * TOPK * 4);
    float* sg       = (float*)alloc((size_t)N_TOK * 4);
    int*   slot_tok = (int*)  alloc((size_t)SLOTS * 4);
    float* slot_w   = (float*)alloc((size_t)SLOTS * 4);
    unsigned short* h_bf  = (unsigned short*)alloc((size_t)N_TOK * H_DIM * 2);
    unsigned short* wgT   = (unsigned short*)alloc((size_t)E_NUM * IMOE * H_DIM * 2);
    unsigned short* wuT   = (unsigned short*)alloc((size_t)E_NUM * IMOE * H_DIM * 2);
    unsigned short* wdT   = (unsigned short*)alloc((size_t)E_NUM * H_DIM * IMOE * 2);
    unsigned short* shGT  = (unsigned short*)alloc((size_t)ISH * H_DIM * 2);
    unsigned short* shUT  = (unsigned short*)alloc((size_t)ISH * H_DIM * 2);
    unsigned short* shDT  = (unsigned short*)alloc((size_t)H_DIM * ISH * 2);
    unsigned short* Agath = (unsigned short*)alloc((size_t)(SLOTS + MT) * H_DIM * 2);
    unsigned short* actR  = (unsigned short*)alloc((size_t)(SLOTS + MT) * IMOE * 2);
    unsigned short* actS  = (unsigned short*)alloc((size_t)N_TOK * ISH * 2);
    (void)ws_size; (void)in_sizes; (void)n_in; (void)out_size;

    hipMemsetAsync(out, 0, (size_t)N_TOK * H_DIM * 4, stream);
    hipMemsetAsync(counts, 0, E_NUM * 4, stream);

    // bf16 conversions
    cvt_h_kernel<<<(N_TOK * H_DIM / 4 + 255) / 256, 256, 0, stream>>>(h, h_bf, N_TOK * H_DIM / 4);
    transpose_cvt_kernel<<<dim3(IMOE / 32, H_DIM / 32, E_NUM), dim3(32, 8), 0, stream>>>(wg, wgT, H_DIM, IMOE);
    transpose_cvt_kernel<<<dim3(IMOE / 32, H_DIM / 32, E_NUM), dim3(32, 8), 0, stream>>>(wu, wuT, H_DIM, IMOE);
    transpose_cvt_kernel<<<dim3(H_DIM / 32, IMOE / 32, E_NUM), dim3(32, 8), 0, stream>>>(wd, wdT, IMOE, H_DIM);
    transpose_cvt_kernel<<<dim3(ISH / 32, H_DIM / 32, 1), dim3(32, 8), 0, stream>>>(shg, shGT, H_DIM, ISH);
    transpose_cvt_kernel<<<dim3(ISH / 32, H_DIM / 32, 1), dim3(32, 8), 0, stream>>>(shu, shUT, H_DIM, ISH);
    transpose_cvt_kernel<<<dim3(H_DIM / 32, ISH / 32, 1), dim3(32, 8), 0, stream>>>(shd, shDT, ISH, H_DIM);

    // routing
    router_kernel<<<N_TOK, 256, 0, stream>>>(h, rw, sgw, topk_idx, topk_w, sg, counts);
    scan_kernel<<<1, 1, 0, stream>>>(counts, offsets, cursor);
    bucketize_kernel<<<N_TOK / 256, 256, 0, stream>>>(topk_idx, topk_w, cursor, slot_tok, slot_w);
    gather_kernel<<<SLOTS, 256, 0, stream>>>(h_bf, slot_tok, Agath);

    // routed experts: gate/up fused (N-tile 64), then down + atomic combine
    gemm_dual_kernel<<<dim3(IMOE / 64, N_TOK / MT, E_NUM), 256, 0, stream>>>(
        Agath, wgT, wuT, actR, counts, offsets, H_DIM, IMOE, 0);
    // shared expert gate/up
    gemm_dual_kernel<<<dim3(ISH / 64, N_TOK / MT, 1), 256, 0, stream>>>(
        h_bf, shGT, shUT, actS, nullptr, nullptr, H_DIM, ISH, N_TOK);
    // routed down + scatter-combine
    gemm_down_kernel<<<dim3(H_DIM / MT, N_TOK / MT, E_NUM), 256, 0, stream>>>(
        actR, wdT, out, counts, offsets, slot_tok, slot_w, nullptr, IMOE, H_DIM, 0);
    // shared down + sigmoid-gated add
    gemm_down_kernel<<<dim3(H_DIM / MT, N_TOK / MT, 1), 256, 0, stream>>>(
        actS, shDT, out, nullptr, nullptr, nullptr, nullptr, sg, ISH, H_DIM, N_TOK);
}

// Round 3
// 1495.344 us; speedup vs baseline: 1.2762x; 1.1043x over previous
//
#include <hip/hip_runtime.h>
#include <stdint.h>

// Qwen3.5 MoE block: N=4096 tokens, H=2048, E=16, K=4, I_moe=1408, I_sh=5632
// R4 (resubmit; R2 bench was an infra failure): router rewrite. Old router was
// latency-bound (240 us, 76 GB/s, 9% VALU): one token per 256-thread block,
// scalar stride-64B fp32 loads, syncthreads reduction tree. New router:
// 16 tokens/block (4/wave, 16 lanes/token), float4 coalesced h reads,
// rw wave-broadcast (L2-resident), 17 register accumulators, shfl_down
// reduce, bitmask top-4 (no scratch arrays).
// GEMMs unchanged from R3 (supertile+XCD swizzle, BK=64, glds16 + XOR swizzle).

#define N_TOK 4096
#define H_DIM 2048
#define E_NUM 16
#define TOPK  4
#define IMOE  1408
#define ISH   5632
#define SLOTS (N_TOK*TOPK)       // 16384

#define MT 128
#define BK 64                     // bf16 elems along k per tile (128 B, 8 chunks)

typedef __attribute__((ext_vector_type(8))) short bf16x8;   // 8 bf16 = 4 VGPRs
typedef __attribute__((ext_vector_type(4))) float f32x4;

static __device__ inline unsigned short f2bf(float f) {
    union { float f; unsigned u; } v; v.f = f;
    unsigned r = v.u + 0x7fffu + ((v.u >> 16) & 1u);   // RNE
    return (unsigned short)(r >> 16);
}

// async global->LDS, 16 bytes per lane. LDS dest = wave-uniform base + lane*16.
static __device__ inline void glds16(const unsigned short* g, unsigned short* l) {
    __builtin_amdgcn_global_load_lds(
        (const __attribute__((address_space(1))) void*)g,
        (__attribute__((address_space(3))) void*)l, 16, 0, 0);
}

// Block-id decode: flat (per-z) id -> (ntile, mtile).
// Step 1: bijective XCD chunking (m204): XCD x = f&7 owns a contiguous chunk
//         of the logical sequence -> consecutive logicals stay on one XCD L2.
// Step 2: supertile order: groups of GM=8 mtiles; within a group mtile varies
//         fastest -> 8 consecutive logicals share one B-tile (ntile).
static __device__ inline bool decode_tile(int bx, int by, int NX, int NYact,
                                          int& nt, int& mt) {
    int f = by * NX + bx;
    int NB = NX * NYact;
    if (f >= NB) return false;
    int q = NB >> 3, rr = NB & 7;
    int x = f & 7, s = f >> 3;
    int L = (x < rr ? x * (q + 1) : rr * (q + 1) + (x - rr) * q) + s;
    const int GM = 8;
    int G = GM * NX;
    int g = L / G, r2 = L - g * G;
    int gm = NYact - g * GM; if (gm > GM) gm = GM;
    nt = r2 / gm;
    mt = g * GM + (r2 - nt * gm);
    return true;
}

// ---------------- fp32 -> bf16 (no transpose), for hidden_states ----------------
__global__ void cvt_h_kernel(const float* __restrict__ in, unsigned short* __restrict__ out, int n4) {
    int i = blockIdx.x * blockDim.x + threadIdx.x;
    if (i < n4) {
        float4 v = *(const float4*)(in + (size_t)i * 4);
        ushort4 o; o.x = f2bf(v.x); o.y = f2bf(v.y); o.z = f2bf(v.z); o.w = f2bf(v.w);
        *(ushort4*)(out + (size_t)i * 4) = o;
    }
}

// ---------------- fp32 [R,C] -> bf16 [C,R] (per z-slice) ----------------
__global__ void transpose_cvt_kernel(const float* __restrict__ in, unsigned short* __restrict__ out,
                                     int R, int C) {
    __shared__ float tile[32][33];
    const float* ip = in + (size_t)blockIdx.z * R * C;
    unsigned short* op = out + (size_t)blockIdx.z * R * C;
    int cb = blockIdx.x * 32, rb = blockIdx.y * 32;
    int tx = threadIdx.x, ty = threadIdx.y;            // (32, 8)
    for (int i = 0; i < 4; i++)
        tile[ty + i * 8][tx] = ip[(size_t)(rb + ty + i * 8) * C + cb + tx];
    __syncthreads();
    for (int i = 0; i < 4; i++)
        op[(size_t)(cb + ty + i * 8) * R + rb + tx] = f2bf(tile[tx][ty + i * 8]);
}

// ---------------- router: 16 tokens/block, float4 loads, shfl reduce ----------------
// logits = h @ rw^T (16) plus shared-gate dot (1) -> 17 accumulators/lane.
// Lane layout: wave handles 4 tokens; 16 lanes per token; lane 'part' covers
// j = i*64 + part*4 (contiguous 256B per 16-lane group per iter -> coalesced;
// rw reads are identical across the 4 token-groups -> broadcast, L2-resident).
__global__ __launch_bounds__(256) void router_kernel(
    const float* __restrict__ h, const float* __restrict__ rw, const float* __restrict__ gw,
    int* __restrict__ topk_idx, float* __restrict__ topk_w,
    float* __restrict__ sg, int* __restrict__ counts) {
    int t = threadIdx.x;
    int wv = t >> 6, lane = t & 63;
    int tokw = lane >> 4, part = lane & 15;
    int n = blockIdx.x * 16 + wv * 4 + tokw;
    const float* hp = h + (size_t)n * H_DIM;

    float acc[17];
#pragma unroll
    for (int e = 0; e < 17; e++) acc[e] = 0.f;

    for (int i = 0; i < 32; i++) {
        int j = i * 64 + part * 4;
        float4 hv = *(const float4*)(hp + j);
#pragma unroll
        for (int e = 0; e < E_NUM; e++) {
            float4 w4 = *(const float4*)(rw + (size_t)e * H_DIM + j);
            acc[e] += hv.x * w4.x + hv.y * w4.y + hv.z * w4.z + hv.w * w4.w;
        }
        float4 g4 = *(const float4*)(gw + j);
        acc[16] += hv.x * g4.x + hv.y * g4.y + hv.z * g4.z + hv.w * g4.w;
    }
    // reduce across the 16 lanes of each token group
#pragma unroll
    for (int d = 8; d; d >>= 1)
#pragma unroll
        for (int e = 0; e < 17; e++)
            acc[e] += __shfl_down(acc[e], d, 16);

    if (part == 0) {
        float m = acc[0];
#pragma unroll
        for (int i = 1; i < E_NUM; i++) m = fmaxf(m, acc[i]);
        float p[E_NUM]; float s = 0.f;
#pragma unroll
        for (int i = 0; i < E_NUM; i++) { p[i] = expf(acc[i] - m); s += p[i]; }
        float invs = 1.f / s;
#pragma unroll
        for (int i = 0; i < E_NUM; i++) p[i] *= invs;
        // top-4 via used-bitmask (no dynamic-indexed stores -> stays in regs)
        int idx[TOPK]; float val[TOPK]; float vs = 0.f; unsigned used = 0;
#pragma unroll
        for (int k = 0; k < TOPK; k++) {
            int bi = 0; float bv = -1.f;
#pragma unroll
            for (int i = 0; i < E_NUM; i++)
                if (!((used >> i) & 1u) && p[i] > bv) { bv = p[i]; bi = i; }
            idx[k] = bi; val[k] = bv; vs += bv; used |= (1u << bi);
        }
        float inv = 1.f / fmaxf(vs, 1e-9f);
#pragma unroll
        for (int k = 0; k < TOPK; k++) {
            topk_idx[n * TOPK + k] = idx[k];
            topk_w[n * TOPK + k] = val[k] * inv;
            atomicAdd(&counts[idx[k]], 1);
        }
        sg[n] = 1.f / (1.f + expf(-acc[16]));
    }
}

// ---------------- exclusive scan of 16 counts (tiny) ----------------
__global__ void scan_kernel(const int* __restrict__ counts, int* __restrict__ offsets,
                            int* __restrict__ cursor) {
    int s = 0;
    for (int e = 0; e < E_NUM; e++) { offsets[e] = s; cursor[e] = s; s += counts[e]; }
}

// ---------------- scatter token->slot ----------------
__global__ void bucketize_kernel(const int* __restrict__ topk_idx, const float* __restrict__ topk_w,
                                 int* __restrict__ cursor, int* __restrict__ slot_tok,
                                 float* __restrict__ slot_w) {
    int n = blockIdx.x * blockDim.x + threadIdx.x;
    if (n >= N_TOK) return;
    for (int k = 0; k < TOPK; k++) {
        int e = topk_idx[n * TOPK + k];
        int s = atomicAdd(&cursor[e], 1);
        slot_tok[s] = n;
        slot_w[s] = topk_w[n * TOPK + k];
    }
}

// ---------------- gather bf16 token rows into slot order ----------------
__global__ __launch_bounds__(256) void gather_kernel(const unsigned short* __restrict__ hbf,
                                                     const int* __restrict__ slot_tok,
                                                     unsigned short* __restrict__ A) {
    int s = blockIdx.x;
    int tok = slot_tok[s];
    const uint4* src = (const uint4*)(hbf + (size_t)tok * H_DIM);
    uint4* dst = (uint4*)(A + (size_t)s * H_DIM);
    dst[threadIdx.x] = src[threadIdx.x];
}

// ---------------- fused gate/up GEMM + SiLU*mul -> bf16 act ----------------
// Block tile: 128 rows x 64 cols, dual accumulators (gate & up share A-frags).
// Per wave (2x2 grid): 64x32, accg[4][2]+accu[4][2] = 64 AGPR.
// BK=64: per thread 8x glds16/iter; XOR chunk swizzle p = l ^ (row&7).
__global__ __launch_bounds__(256, 2) void gemm_dual_kernel(
    const unsigned short* __restrict__ A, const unsigned short* __restrict__ Bg,
    const unsigned short* __restrict__ Bu, unsigned short* __restrict__ act,
    const int* __restrict__ counts, const int* __restrict__ offsets,
    int K, int N, int fixedM) {
    int e = blockIdx.z;
    int c, off;
    if (counts) { c = counts[e]; off = offsets[e]; } else { c = fixedM; off = 0; }
    int NYact = (c + MT - 1) / MT;
    int nt, mt;
    if (!decode_tile(blockIdx.x, blockIdx.y, gridDim.x, NYact, nt, mt)) return;

    const unsigned short* Ab = A + (size_t)off * K;
    const unsigned short* Bgb = Bg + (size_t)e * (size_t)N * K;
    const unsigned short* Bub = Bu + (size_t)e * (size_t)N * K;
    unsigned short* actb = act + (size_t)off * N;

    __shared__ __align__(16) unsigned short As[MT * BK];      // 16 KB
    __shared__ __align__(16) unsigned short Bgs[64 * BK];     // 8 KB
    __shared__ __align__(16) unsigned short Bus[64 * BK];     // 8 KB

    int t = threadIdx.x;
    int wave = t >> 6, lane = t & 63;
    int wm = wave >> 1, wn = wave & 1;
    int quad = lane >> 4, l16 = lane & 15;

    f32x4 accg[4][2], accu[4][2];
    for (int i = 0; i < 4; i++) for (int j = 0; j < 2; j++) { accg[i][j] = (f32x4)0.f; accu[i][j] = (f32x4)0.f; }

    int m0 = mt * MT, n0 = nt * 64;
    // staging slot assignments (constant across k-steps): physical chunk s
    // holds logical chunk (s&7)^(row&7) of its row.
    int rA[4], cA[4];
    for (int j = 0; j < 4; j++) { int s = t + 256 * j; rA[j] = s >> 3; cA[j] = (s & 7) ^ (rA[j] & 7); }
    int rB[2], cB[2];
    for (int j = 0; j < 2; j++) { int s = t + 256 * j; rB[j] = s >> 3; cB[j] = (s & 7) ^ (rB[j] & 7); }

    for (int kt = 0; kt < K; kt += BK) {
        __syncthreads();
        for (int j = 0; j < 4; j++)
            glds16(&Ab[(size_t)(m0 + rA[j]) * K + kt + cA[j] * 8], &As[(t + 256 * j) * 8]);
        for (int j = 0; j < 2; j++) {
            glds16(&Bgb[(size_t)(n0 + rB[j]) * K + kt + cB[j] * 8], &Bgs[(t + 256 * j) * 8]);
            glds16(&Bub[(size_t)(n0 + rB[j]) * K + kt + cB[j] * 8], &Bus[(t + 256 * j) * 8]);
        }
        __syncthreads();
#pragma unroll
        for (int ks = 0; ks < 2; ks++) {
            int lbase = (ks << 2) | quad;
            bf16x8 af[4], bgf[2], buf[2];
            for (int mi = 0; mi < 4; mi++) {
                int rowl = wm * 64 + mi * 16 + l16;
                af[mi] = *(const bf16x8*)&As[rowl * BK + ((lbase ^ (rowl & 7)) * 8)];
            }
            for (int ni = 0; ni < 2; ni++) {
                int rowl = wn * 32 + ni * 16 + l16;
                int co = (lbase ^ (rowl & 7)) * 8;
                bgf[ni] = *(const bf16x8*)&Bgs[rowl * BK + co];
                buf[ni] = *(const bf16x8*)&Bus[rowl * BK + co];
            }
            for (int mi = 0; mi < 4; mi++)
                for (int ni = 0; ni < 2; ni++) {
                    accg[mi][ni] = __builtin_amdgcn_mfma_f32_16x16x32_bf16(af[mi], bgf[ni], accg[mi][ni], 0, 0, 0);
                    accu[mi][ni] = __builtin_amdgcn_mfma_f32_16x16x32_bf16(af[mi], buf[ni], accu[mi][ni], 0, 0, 0);
                }
        }
    }
    for (int mi = 0; mi < 4; mi++) {
        for (int r = 0; r < 4; r++) {
            int rl = m0 + wm * 64 + mi * 16 + quad * 4 + r;
            if (rl < c) {
                size_t rowbase = (size_t)rl * N + n0 + wn * 32 + l16;
                for (int ni = 0; ni < 2; ni++) {
                    float g = accg[mi][ni][r];
                    float u = accu[mi][ni][r];
                    float a = (g / (1.f + __expf(-g))) * u;
                    actb[rowbase + ni * 16] = f2bf(a);
                }
            }
        }
    }
}

// ---------------- down GEMM + combine ----------------
// 128x128 tile, per wave 64x64, acc[4][4] = 64 AGPR. BK=64 + swizzle staging.
// routed: atomicAdd(out[tok,:], w_slot * y). shared: out[row,:] += sg[row] * y.
__global__ __launch_bounds__(256, 2) void gemm_down_kernel(
    const unsigned short* __restrict__ Aact, const unsigned short* __restrict__ Bd,
    float* __restrict__ out,
    const int* __restrict__ counts, const int* __restrict__ offsets,
    const int* __restrict__ slot_tok, const float* __restrict__ slot_w,
    const float* __restrict__ sg,
    int K, int N, int fixedM) {
    int e = blockIdx.z;
    bool routed = (counts != nullptr);
    int c, off;
    if (routed) { c = counts[e]; off = offsets[e]; } else { c = fixedM; off = 0; }
    int NYact = (c + MT - 1) / MT;
    int nt, mt;
    if (!decode_tile(blockIdx.x, blockIdx.y, gridDim.x, NYact, nt, mt)) return;

    const unsigned short* Ab = Aact + (size_t)off * K;
    const unsigned short* Bb = Bd + (size_t)e * (size_t)N * K;

    __shared__ __align__(16) unsigned short As[MT * BK];      // 16 KB
    __shared__ __align__(16) unsigned short Bs[MT * BK];      // 16 KB

    int t = threadIdx.x;
    int wave = t >> 6, lane = t & 63;
    int wm = wave >> 1, wn = wave & 1;
    int quad = lane >> 4, l16 = lane & 15;

    f32x4 acc[4][4];
    for (int i = 0; i < 4; i++) for (int j = 0; j < 4; j++) acc[i][j] = (f32x4)0.f;

    int m0 = mt * MT, n0 = nt * MT;
    int rA[4], cA[4];
    for (int j = 0; j < 4; j++) { int s = t + 256 * j; rA[j] = s >> 3; cA[j] = (s & 7) ^ (rA[j] & 7); }

    for (int kt = 0; kt < K; kt += BK) {
        __syncthreads();
        for (int j = 0; j < 4; j++) {
            glds16(&Ab[(size_t)(m0 + rA[j]) * K + kt + cA[j] * 8], &As[(t + 256 * j) * 8]);
            glds16(&Bb[(size_t)(n0 + rA[j]) * K + kt + cA[j] * 8], &Bs[(t + 256 * j) * 8]);
        }
        __syncthreads();
#pragma unroll
        for (int ks = 0; ks < 2; ks++) {
            int lbase = (ks << 2) | quad;
            bf16x8 af[4], bf[4];
            for (int mi = 0; mi < 4; mi++) {
                int rowl = wm * 64 + mi * 16 + l16;
                af[mi] = *(const bf16x8*)&As[rowl * BK + ((lbase ^ (rowl & 7)) * 8)];
            }
            for (int ni = 0; ni < 4; ni++) {
                int rowl = wn * 64 + ni * 16 + l16;
                bf[ni] = *(const bf16x8*)&Bs[rowl * BK + ((lbase ^ (rowl & 7)) * 8)];
            }
            for (int mi = 0; mi < 4; mi++)
                for (int ni = 0; ni < 4; ni++)
                    acc[mi][ni] = __builtin_amdgcn_mfma_f32_16x16x32_bf16(af[mi], bf[ni], acc[mi][ni], 0, 0, 0);
        }
    }
    for (int mi = 0; mi < 4; mi++) {
        for (int r = 0; r < 4; r++) {
            int rl = m0 + wm * 64 + mi * 16 + quad * 4 + r;
            if (rl < c) {
                int col = n0 + wn * 64 + l16;
                if (routed) {
                    int s = off + rl;
                    int tok = slot_tok[s];
                    float w = slot_w[s];
                    float* ob = out + (size_t)tok * N + col;
                    for (int ni = 0; ni < 4; ni++)
                        atomicAdd(ob + ni * 16, w * acc[mi][ni][r]);
                } else {
                    float w = sg[rl];
                    float* ob = out + (size_t)rl * N + col;
                    for (int ni = 0; ni < 4; ni++)
                        ob[ni * 16] += w * acc[mi][ni][r];
                }
            }
        }
    }
}

extern "C" void kernel_launch(void* const* d_in, const int* in_sizes, int n_in,
                              void* d_out, int out_size, void* d_ws, size_t ws_size,
                              hipStream_t stream) {
    const float* h   = (const float*)d_in[0];
    const float* rw  = (const float*)d_in[1];
    const float* wg  = (const float*)d_in[2];
    const float* wu  = (const float*)d_in[3];
    const float* wd  = (const float*)d_in[4];
    const float* shg = (const float*)d_in[5];
    const float* shu = (const float*)d_in[6];
    const float* shd = (const float*)d_in[7];
    const float* sgw = (const float*)d_in[8];
    float* out = (float*)d_out;

    char* ws = (char*)d_ws;
    size_t off = 0;
    auto alloc = [&](size_t b) { size_t o = off; off += (b + 255) & ~(size_t)255; return (void*)(ws + o); };

    int*   counts   = (int*)  alloc(E_NUM * 4);
    int*   offsets  = (int*)  alloc(E_NUM * 4);
    int*   cursor   = (int*)  alloc(E_NUM * 4);
    int*   topk_idx = (int*)  alloc((size_t)N_TOK * TOPK * 4);
    float* topk_w   = (float*)alloc((size_t)N_TOK * TOPK * 4);
    float* sg       = (float*)alloc((size_t)N_TOK * 4);
    int*   slot_tok = (int*)  alloc((size_t)SLOTS * 4);
    float* slot_w   = (float*)alloc((size_t)SLOTS * 4);
    unsigned short* h_bf  = (unsigned short*)alloc((size_t)N_TOK * H_DIM * 2);
    unsigned short* wgT   = (unsigned short*)alloc((size_t)E_NUM * IMOE * H_DIM * 2);
    unsigned short* wuT   = (unsigned short*)alloc((size_t)E_NUM * IMOE * H_DIM * 2);
    unsigned short* wdT   = (unsigned short*)alloc((size_t)E_NUM * H_DIM * IMOE * 2);
    unsigned short* shGT  = (unsigned short*)alloc((size_t)ISH * H_DIM * 2);
    unsigned short* shUT  = (unsigned short*)alloc((size_t)ISH * H_DIM * 2);
    unsigned short* shDT  = (unsigned short*)alloc((size_t)H_DIM * ISH * 2);
    unsigned short* Agath = (unsigned short*)alloc((size_t)(SLOTS + MT) * H_DIM * 2);
    unsigned short* actR  = (unsigned short*)alloc((size_t)(SLOTS + MT) * IMOE * 2);
    unsigned short* actS  = (unsigned short*)alloc((size_t)N_TOK * ISH * 2);
    (void)ws_size; (void)in_sizes; (void)n_in; (void)out_size;

    hipMemsetAsync(out, 0, (size_t)N_TOK * H_DIM * 4, stream);
    hipMemsetAsync(counts, 0, E_NUM * 4, stream);

    // bf16 conversions
    cvt_h_kernel<<<(N_TOK * H_DIM / 4 + 255) / 256, 256, 0, stream>>>(h, h_bf, N_TOK * H_DIM / 4);
    transpose_cvt_kernel<<<dim3(IMOE / 32, H_DIM / 32, E_NUM), dim3(32, 8), 0, stream>>>(wg, wgT, H_DIM, IMOE);
    transpose_cvt_kernel<<<dim3(IMOE / 32, H_DIM / 32, E_NUM), dim3(32, 8), 0, stream>>>(wu, wuT, H_DIM, IMOE);
    transpose_cvt_kernel<<<dim3(H_DIM / 32, IMOE / 32, E_NUM), dim3(32, 8), 0, stream>>>(wd, wdT, IMOE, H_DIM);
    transpose_cvt_kernel<<<dim3(ISH / 32, H_DIM / 32, 1), dim3(32, 8), 0, stream>>>(shg, shGT, H_DIM, ISH);
    transpose_cvt_kernel<<<dim3(ISH / 32, H_DIM / 32, 1), dim3(32, 8), 0, stream>>>(shu, shUT, H_DIM, ISH);
    transpose_cvt_kernel<<<dim3(H_DIM / 32, ISH / 32, 1), dim3(32, 8), 0, stream>>>(shd, shDT, ISH, H_DIM);

    // routing
    router_kernel<<<N_TOK / 16, 256, 0, stream>>>(h, rw, sgw, topk_idx, topk_w, sg, counts);
    scan_kernel<<<1, 1, 0, stream>>>(counts, offsets, cursor);
    bucketize_kernel<<<N_TOK / 256, 256, 0, stream>>>(topk_idx, topk_w, cursor, slot_tok, slot_w);
    gather_kernel<<<SLOTS, 256, 0, stream>>>(h_bf, slot_tok, Agath);

    // routed experts: gate/up fused (N-tile 64), then down + atomic combine
    gemm_dual_kernel<<<dim3(IMOE / 64, N_TOK / MT, E_NUM), 256, 0, stream>>>(
        Agath, wgT, wuT, actR, counts, offsets, H_DIM, IMOE, 0);
    // shared expert gate/up
    gemm_dual_kernel<<<dim3(ISH / 64, N_TOK / MT, 1), 256, 0, stream>>>(
        h_bf, shGT, shUT, actS, nullptr, nullptr, H_DIM, ISH, N_TOK);
    // routed down + scatter-combine
    gemm_down_kernel<<<dim3(H_DIM / MT, N_TOK / MT, E_NUM), 256, 0, stream>>>(
        actR, wdT, out, counts, offsets, slot_tok, slot_w, nullptr, IMOE, H_DIM, 0);
    // shared down + sigmoid-gated add
    gemm_down_kernel<<<dim3(H_DIM / MT, N_TOK / MT, 1), 256, 0, stream>>>(
        actS, shDT, out, nullptr, nullptr, nullptr, nullptr, sg, ISH, H_DIM, N_TOK);
}

// Round 4
// 1459.109 us; speedup vs baseline: 1.3079x; 1.0248x over previous
//
#include <hip/hip_runtime.h>
#include <stdint.h>

// Qwen3.5 MoE block: N=4096 tokens, H=2048, E=16, K=4, I_moe=1408, I_sh=5632
// R5: (1) de-atomized down path: gemm_down writes raw fp32 rows (ySlot/ySh),
// combine_kernel does out = sum_k w_k*ySlot[slot(n,k)] + sg*ySh (no atomics,
// no fp32 RMW, no out memset). ySh aliases dead actR. (2) transpose_cvt:
// 64x64 tiles, float4 loads + ushort4 stores (was 2B/lane stores).
// GEMM cores unchanged from R3/R4 (supertile+XCD swizzle, BK=64, glds16+XOR).

#define N_TOK 4096
#define H_DIM 2048
#define E_NUM 16
#define TOPK  4
#define IMOE  1408
#define ISH   5632
#define SLOTS (N_TOK*TOPK)       // 16384

#define MT 128
#define BK 64                     // bf16 elems along k per tile (128 B, 8 chunks)

typedef __attribute__((ext_vector_type(8))) short bf16x8;   // 8 bf16 = 4 VGPRs
typedef __attribute__((ext_vector_type(4))) float f32x4;

static __device__ inline unsigned short f2bf(float f) {
    union { float f; unsigned u; } v; v.f = f;
    unsigned r = v.u + 0x7fffu + ((v.u >> 16) & 1u);   // RNE
    return (unsigned short)(r >> 16);
}

// async global->LDS, 16 bytes per lane. LDS dest = wave-uniform base + lane*16.
static __device__ inline void glds16(const unsigned short* g, unsigned short* l) {
    __builtin_amdgcn_global_load_lds(
        (const __attribute__((address_space(1))) void*)g,
        (__attribute__((address_space(3))) void*)l, 16, 0, 0);
}

// Block-id decode: flat (per-z) id -> (ntile, mtile).
// Step 1: bijective XCD chunking (m204). Step 2: supertile order, GM=8 mtiles
// per group (mtile fastest) -> consecutive same-XCD blocks share one B-tile.
static __device__ inline bool decode_tile(int bx, int by, int NX, int NYact,
                                          int& nt, int& mt) {
    int f = by * NX + bx;
    int NB = NX * NYact;
    if (f >= NB) return false;
    int q = NB >> 3, rr = NB & 7;
    int x = f & 7, s = f >> 3;
    int L = (x < rr ? x * (q + 1) : rr * (q + 1) + (x - rr) * q) + s;
    const int GM = 8;
    int G = GM * NX;
    int g = L / G, r2 = L - g * G;
    int gm = NYact - g * GM; if (gm > GM) gm = GM;
    nt = r2 / gm;
    mt = g * GM + (r2 - nt * gm);
    return true;
}

// ---------------- fp32 -> bf16 (no transpose), for hidden_states ----------------
__global__ void cvt_h_kernel(const float* __restrict__ in, unsigned short* __restrict__ out, int n4) {
    int i = blockIdx.x * blockDim.x + threadIdx.x;
    if (i < n4) {
        float4 v = *(const float4*)(in + (size_t)i * 4);
        ushort4 o; o.x = f2bf(v.x); o.y = f2bf(v.y); o.z = f2bf(v.z); o.w = f2bf(v.w);
        *(ushort4*)(out + (size_t)i * 4) = o;
    }
}

// ---------------- fp32 [R,C] -> bf16 [C,R] (per z-slice), 64x64 tiles ----------------
// 256 threads. Load: 16 lanes x float4 = 256B per input row, 16 rows/pass.
// Store: 16 lanes x ushort4 = 128B per output row, 16 rows/pass.
// LDS pad 65 -> <=2-way banks on both phases (free).
__global__ __launch_bounds__(256) void transpose_cvt_kernel(
    const float* __restrict__ in, unsigned short* __restrict__ out, int R, int C) {
    __shared__ float tile[64][65];
    const float* ip = in + (size_t)blockIdx.z * R * C;
    unsigned short* op = out + (size_t)blockIdx.z * R * C;
    int cb = blockIdx.x * 64, rb = blockIdx.y * 64;
    int tid = threadIdx.x;
    int lr = tid >> 4, lc = tid & 15;
#pragma unroll
    for (int p = 0; p < 4; p++) {
        int r = p * 16 + lr;
        float4 v = *(const float4*)(ip + (size_t)(rb + r) * C + cb + lc * 4);
        tile[r][lc * 4 + 0] = v.x;
        tile[r][lc * 4 + 1] = v.y;
        tile[r][lc * 4 + 2] = v.z;
        tile[r][lc * 4 + 3] = v.w;
    }
    __syncthreads();
#pragma unroll
    for (int p = 0; p < 4; p++) {
        int oc = p * 16 + lr;            // output row = source column
        ushort4 o;
        o.x = f2bf(tile[lc * 4 + 0][oc]);
        o.y = f2bf(tile[lc * 4 + 1][oc]);
        o.z = f2bf(tile[lc * 4 + 2][oc]);
        o.w = f2bf(tile[lc * 4 + 3][oc]);
        *(ushort4*)(op + (size_t)(cb + oc) * R + rb + lc * 4) = o;
    }
}

// ---------------- router: 16 tokens/block, float4 loads, shfl reduce ----------------
__global__ __launch_bounds__(256) void router_kernel(
    const float* __restrict__ h, const float* __restrict__ rw, const float* __restrict__ gw,
    int* __restrict__ topk_idx, float* __restrict__ topk_w,
    float* __restrict__ sg, int* __restrict__ counts) {
    int t = threadIdx.x;
    int wv = t >> 6, lane = t & 63;
    int tokw = lane >> 4, part = lane & 15;
    int n = blockIdx.x * 16 + wv * 4 + tokw;
    const float* hp = h + (size_t)n * H_DIM;

    float acc[17];
#pragma unroll
    for (int e = 0; e < 17; e++) acc[e] = 0.f;

    for (int i = 0; i < 32; i++) {
        int j = i * 64 + part * 4;
        float4 hv = *(const float4*)(hp + j);
#pragma unroll
        for (int e = 0; e < E_NUM; e++) {
            float4 w4 = *(const float4*)(rw + (size_t)e * H_DIM + j);
            acc[e] += hv.x * w4.x + hv.y * w4.y + hv.z * w4.z + hv.w * w4.w;
        }
        float4 g4 = *(const float4*)(gw + j);
        acc[16] += hv.x * g4.x + hv.y * g4.y + hv.z * g4.z + hv.w * g4.w;
    }
#pragma unroll
    for (int d = 8; d; d >>= 1)
#pragma unroll
        for (int e = 0; e < 17; e++)
            acc[e] += __shfl_down(acc[e], d, 16);

    if (part == 0) {
        float m = acc[0];
#pragma unroll
        for (int i = 1; i < E_NUM; i++) m = fmaxf(m, acc[i]);
        float p[E_NUM]; float s = 0.f;
#pragma unroll
        for (int i = 0; i < E_NUM; i++) { p[i] = expf(acc[i] - m); s += p[i]; }
        float invs = 1.f / s;
#pragma unroll
        for (int i = 0; i < E_NUM; i++) p[i] *= invs;
        int idx[TOPK]; float val[TOPK]; float vs = 0.f; unsigned used = 0;
#pragma unroll
        for (int k = 0; k < TOPK; k++) {
            int bi = 0; float bv = -1.f;
#pragma unroll
            for (int i = 0; i < E_NUM; i++)
                if (!((used >> i) & 1u) && p[i] > bv) { bv = p[i]; bi = i; }
            idx[k] = bi; val[k] = bv; vs += bv; used |= (1u << bi);
        }
        float inv = 1.f / fmaxf(vs, 1e-9f);
#pragma unroll
        for (int k = 0; k < TOPK; k++) {
            topk_idx[n * TOPK + k] = idx[k];
            topk_w[n * TOPK + k] = val[k] * inv;
            atomicAdd(&counts[idx[k]], 1);
        }
        sg[n] = 1.f / (1.f + expf(-acc[16]));
    }
}

// ---------------- exclusive scan of 16 counts (tiny) ----------------
__global__ void scan_kernel(const int* __restrict__ counts, int* __restrict__ offsets,
                            int* __restrict__ cursor) {
    int s = 0;
    for (int e = 0; e < E_NUM; e++) { offsets[e] = s; cursor[e] = s; s += counts[e]; }
}

// ---------------- scatter token->slot (+ inverse map token->slot ids) ----------------
__global__ void bucketize_kernel(const int* __restrict__ topk_idx,
                                 int* __restrict__ cursor, int* __restrict__ slot_tok,
                                 int* __restrict__ tok_slot) {
    int n = blockIdx.x * blockDim.x + threadIdx.x;
    if (n >= N_TOK) return;
    for (int k = 0; k < TOPK; k++) {
        int e = topk_idx[n * TOPK + k];
        int s = atomicAdd(&cursor[e], 1);
        slot_tok[s] = n;
        tok_slot[n * TOPK + k] = s;
    }
}

// ---------------- gather bf16 token rows into slot order ----------------
__global__ __launch_bounds__(256) void gather_kernel(const unsigned short* __restrict__ hbf,
                                                     const int* __restrict__ slot_tok,
                                                     unsigned short* __restrict__ A) {
    int s = blockIdx.x;
    int tok = slot_tok[s];
    const uint4* src = (const uint4*)(hbf + (size_t)tok * H_DIM);
    uint4* dst = (uint4*)(A + (size_t)s * H_DIM);
    dst[threadIdx.x] = src[threadIdx.x];
}

// ---------------- fused gate/up GEMM + SiLU*mul -> bf16 act ----------------
__global__ __launch_bounds__(256, 2) void gemm_dual_kernel(
    const unsigned short* __restrict__ A, const unsigned short* __restrict__ Bg,
    const unsigned short* __restrict__ Bu, unsigned short* __restrict__ act,
    const int* __restrict__ counts, const int* __restrict__ offsets,
    int K, int N, int fixedM) {
    int e = blockIdx.z;
    int c, off;
    if (counts) { c = counts[e]; off = offsets[e]; } else { c = fixedM; off = 0; }
    int NYact = (c + MT - 1) / MT;
    int nt, mt;
    if (!decode_tile(blockIdx.x, blockIdx.y, gridDim.x, NYact, nt, mt)) return;

    const unsigned short* Ab = A + (size_t)off * K;
    const unsigned short* Bgb = Bg + (size_t)e * (size_t)N * K;
    const unsigned short* Bub = Bu + (size_t)e * (size_t)N * K;
    unsigned short* actb = act + (size_t)off * N;

    __shared__ __align__(16) unsigned short As[MT * BK];      // 16 KB
    __shared__ __align__(16) unsigned short Bgs[64 * BK];     // 8 KB
    __shared__ __align__(16) unsigned short Bus[64 * BK];     // 8 KB

    int t = threadIdx.x;
    int wave = t >> 6, lane = t & 63;
    int wm = wave >> 1, wn = wave & 1;
    int quad = lane >> 4, l16 = lane & 15;

    f32x4 accg[4][2], accu[4][2];
    for (int i = 0; i < 4; i++) for (int j = 0; j < 2; j++) { accg[i][j] = (f32x4)0.f; accu[i][j] = (f32x4)0.f; }

    int m0 = mt * MT, n0 = nt * 64;
    int rA[4], cA[4];
    for (int j = 0; j < 4; j++) { int s = t + 256 * j; rA[j] = s >> 3; cA[j] = (s & 7) ^ (rA[j] & 7); }
    int rB[2], cB[2];
    for (int j = 0; j < 2; j++) { int s = t + 256 * j; rB[j] = s >> 3; cB[j] = (s & 7) ^ (rB[j] & 7); }

    for (int kt = 0; kt < K; kt += BK) {
        __syncthreads();
        for (int j = 0; j < 4; j++)
            glds16(&Ab[(size_t)(m0 + rA[j]) * K + kt + cA[j] * 8], &As[(t + 256 * j) * 8]);
        for (int j = 0; j < 2; j++) {
            glds16(&Bgb[(size_t)(n0 + rB[j]) * K + kt + cB[j] * 8], &Bgs[(t + 256 * j) * 8]);
            glds16(&Bub[(size_t)(n0 + rB[j]) * K + kt + cB[j] * 8], &Bus[(t + 256 * j) * 8]);
        }
        __syncthreads();
#pragma unroll
        for (int ks = 0; ks < 2; ks++) {
            int lbase = (ks << 2) | quad;
            bf16x8 af[4], bgf[2], buf[2];
            for (int mi = 0; mi < 4; mi++) {
                int rowl = wm * 64 + mi * 16 + l16;
                af[mi] = *(const bf16x8*)&As[rowl * BK + ((lbase ^ (rowl & 7)) * 8)];
            }
            for (int ni = 0; ni < 2; ni++) {
                int rowl = wn * 32 + ni * 16 + l16;
                int co = (lbase ^ (rowl & 7)) * 8;
                bgf[ni] = *(const bf16x8*)&Bgs[rowl * BK + co];
                buf[ni] = *(const bf16x8*)&Bus[rowl * BK + co];
            }
            for (int mi = 0; mi < 4; mi++)
                for (int ni = 0; ni < 2; ni++) {
                    accg[mi][ni] = __builtin_amdgcn_mfma_f32_16x16x32_bf16(af[mi], bgf[ni], accg[mi][ni], 0, 0, 0);
                    accu[mi][ni] = __builtin_amdgcn_mfma_f32_16x16x32_bf16(af[mi], buf[ni], accu[mi][ni], 0, 0, 0);
                }
        }
    }
    for (int mi = 0; mi < 4; mi++) {
        for (int r = 0; r < 4; r++) {
            int rl = m0 + wm * 64 + mi * 16 + quad * 4 + r;
            if (rl < c) {
                size_t rowbase = (size_t)rl * N + n0 + wn * 32 + l16;
                for (int ni = 0; ni < 2; ni++) {
                    float g = accg[mi][ni][r];
                    float u = accu[mi][ni][r];
                    float a = (g / (1.f + __expf(-g))) * u;
                    actb[rowbase + ni * 16] = f2bf(a);
                }
            }
        }
    }
}

// ---------------- down GEMM -> raw fp32 rows (no atomics, no scaling) ----------------
// 128x128 tile, per wave 64x64, acc[4][4] = 64 AGPR. BK=64 + swizzle staging.
// Y[off+row, :] = A_act[off+row,:] @ Bd[e]^T  (combine applies weights later)
__global__ __launch_bounds__(256, 2) void gemm_down_kernel(
    const unsigned short* __restrict__ Aact, const unsigned short* __restrict__ Bd,
    float* __restrict__ Y,
    const int* __restrict__ counts, const int* __restrict__ offsets,
    int K, int N, int fixedM) {
    int e = blockIdx.z;
    int c, off;
    if (counts) { c = counts[e]; off = offsets[e]; } else { c = fixedM; off = 0; }
    int NYact = (c + MT - 1) / MT;
    int nt, mt;
    if (!decode_tile(blockIdx.x, blockIdx.y, gridDim.x, NYact, nt, mt)) return;

    const unsigned short* Ab = Aact + (size_t)off * K;
    const unsigned short* Bb = Bd + (size_t)e * (size_t)N * K;

    __shared__ __align__(16) unsigned short As[MT * BK];      // 16 KB
    __shared__ __align__(16) unsigned short Bs[MT * BK];      // 16 KB

    int t = threadIdx.x;
    int wave = t >> 6, lane = t & 63;
    int wm = wave >> 1, wn = wave & 1;
    int quad = lane >> 4, l16 = lane & 15;

    f32x4 acc[4][4];
    for (int i = 0; i < 4; i++) for (int j = 0; j < 4; j++) acc[i][j] = (f32x4)0.f;

    int m0 = mt * MT, n0 = nt * MT;
    int rA[4], cA[4];
    for (int j = 0; j < 4; j++) { int s = t + 256 * j; rA[j] = s >> 3; cA[j] = (s & 7) ^ (rA[j] & 7); }

    for (int kt = 0; kt < K; kt += BK) {
        __syncthreads();
        for (int j = 0; j < 4; j++) {
            glds16(&Ab[(size_t)(m0 + rA[j]) * K + kt + cA[j] * 8], &As[(t + 256 * j) * 8]);
            glds16(&Bb[(size_t)(n0 + rA[j]) * K + kt + cA[j] * 8], &Bs[(t + 256 * j) * 8]);
        }
        __syncthreads();
#pragma unroll
        for (int ks = 0; ks < 2; ks++) {
            int lbase = (ks << 2) | quad;
            bf16x8 af[4], bf[4];
            for (int mi = 0; mi < 4; mi++) {
                int rowl = wm * 64 + mi * 16 + l16;
                af[mi] = *(const bf16x8*)&As[rowl * BK + ((lbase ^ (rowl & 7)) * 8)];
            }
            for (int ni = 0; ni < 4; ni++) {
                int rowl = wn * 64 + ni * 16 + l16;
                bf[ni] = *(const bf16x8*)&Bs[rowl * BK + ((lbase ^ (rowl & 7)) * 8)];
            }
            for (int mi = 0; mi < 4; mi++)
                for (int ni = 0; ni < 4; ni++)
                    acc[mi][ni] = __builtin_amdgcn_mfma_f32_16x16x32_bf16(af[mi], bf[ni], acc[mi][ni], 0, 0, 0);
        }
    }
    for (int mi = 0; mi < 4; mi++) {
        for (int r = 0; r < 4; r++) {
            int rl = m0 + wm * 64 + mi * 16 + quad * 4 + r;
            if (rl < c) {
                int col = n0 + wn * 64 + l16;
                float* ob = Y + (size_t)(off + rl) * N + col;
                for (int ni = 0; ni < 4; ni++)
                    ob[ni * 16] = acc[mi][ni][r];
            }
        }
    }
}

// ---------------- combine: out[n] = sum_k w_k * ySlot[slot(n,k)] + sg[n] * ySh[n] ----------------
__global__ __launch_bounds__(256) void combine_kernel(
    const float* __restrict__ ySlot, const float* __restrict__ ySh,
    const int* __restrict__ tok_slot, const float* __restrict__ topk_w,
    const float* __restrict__ sgv, float* __restrict__ out) {
    int n = blockIdx.x;
    int s0 = tok_slot[n * TOPK + 0], s1 = tok_slot[n * TOPK + 1];
    int s2 = tok_slot[n * TOPK + 2], s3 = tok_slot[n * TOPK + 3];
    float w0 = topk_w[n * TOPK + 0], w1 = topk_w[n * TOPK + 1];
    float w2 = topk_w[n * TOPK + 2], w3 = topk_w[n * TOPK + 3];
    float g = sgv[n];
    const float4* p0 = (const float4*)(ySlot + (size_t)s0 * H_DIM);
    const float4* p1 = (const float4*)(ySlot + (size_t)s1 * H_DIM);
    const float4* p2 = (const float4*)(ySlot + (size_t)s2 * H_DIM);
    const float4* p3 = (const float4*)(ySlot + (size_t)s3 * H_DIM);
    const float4* ps = (const float4*)(ySh + (size_t)n * H_DIM);
    float4* po = (float4*)(out + (size_t)n * H_DIM);
#pragma unroll
    for (int it = 0; it < H_DIM / 4 / 256; it++) {
        int i = it * 256 + threadIdx.x;
        float4 a = p0[i], b = p1[i], cc = p2[i], d = p3[i], s = ps[i];
        float4 r;
        r.x = w0 * a.x + w1 * b.x + w2 * cc.x + w3 * d.x + g * s.x;
        r.y = w0 * a.y + w1 * b.y + w2 * cc.y + w3 * d.y + g * s.y;
        r.z = w0 * a.z + w1 * b.z + w2 * cc.z + w3 * d.z + g * s.z;
        r.w = w0 * a.w + w1 * b.w + w2 * cc.w + w3 * d.w + g * s.w;
        po[i] = r;
    }
}

extern "C" void kernel_launch(void* const* d_in, const int* in_sizes, int n_in,
                              void* d_out, int out_size, void* d_ws, size_t ws_size,
                              hipStream_t stream) {
    const float* h   = (const float*)d_in[0];
    const float* rw  = (const float*)d_in[1];
    const float* wg  = (const float*)d_in[2];
    const float* wu  = (const float*)d_in[3];
    const float* wd  = (const float*)d_in[4];
    const float* shg = (const float*)d_in[5];
    const float* shu = (const float*)d_in[6];
    const float* shd = (const float*)d_in[7];
    const float* sgw = (const float*)d_in[8];
    float* out = (float*)d_out;

    char* ws = (char*)d_ws;
    size_t off = 0;
    auto alloc = [&](size_t b) { size_t o = off; off += (b + 255) & ~(size_t)255; return (void*)(ws + o); };

    int*   counts   = (int*)  alloc(E_NUM * 4);
    int*   offsets  = (int*)  alloc(E_NUM * 4);
    int*   cursor   = (int*)  alloc(E_NUM * 4);
    int*   topk_idx = (int*)  alloc((size_t)N_TOK * TOPK * 4);
    float* topk_w   = (float*)alloc((size_t)N_TOK * TOPK * 4);
    float* sg       = (float*)alloc((size_t)N_TOK * 4);
    int*   slot_tok = (int*)  alloc((size_t)SLOTS * 4);
    int*   tok_slot = (int*)  alloc((size_t)SLOTS * 4);
    unsigned short* h_bf  = (unsigned short*)alloc((size_t)N_TOK * H_DIM * 2);
    unsigned short* wgT   = (unsigned short*)alloc((size_t)E_NUM * IMOE * H_DIM * 2);
    unsigned short* wuT   = (unsigned short*)alloc((size_t)E_NUM * IMOE * H_DIM * 2);
    unsigned short* wdT   = (unsigned short*)alloc((size_t)E_NUM * H_DIM * IMOE * 2);
    unsigned short* shGT  = (unsigned short*)alloc((size_t)ISH * H_DIM * 2);
    unsigned short* shUT  = (unsigned short*)alloc((size_t)ISH * H_DIM * 2);
    unsigned short* shDT  = (unsigned short*)alloc((size_t)H_DIM * ISH * 2);
    unsigned short* Agath = (unsigned short*)alloc((size_t)(SLOTS + MT) * H_DIM * 2);
    unsigned short* actR  = (unsigned short*)alloc((size_t)(SLOTS + MT) * IMOE * 2);
    unsigned short* actS  = (unsigned short*)alloc((size_t)N_TOK * ISH * 2);
    float* ySlot = (float*)alloc((size_t)SLOTS * H_DIM * 4);
    float* ySh   = (float*)actR;   // actR dead after routed down; 33.5MB <= 46.5MB
    (void)ws_size; (void)in_sizes; (void)n_in; (void)out_size;

    hipMemsetAsync(counts, 0, E_NUM * 4, stream);

    // bf16 conversions
    cvt_h_kernel<<<(N_TOK * H_DIM / 4 + 255) / 256, 256, 0, stream>>>(h, h_bf, N_TOK * H_DIM / 4);
    transpose_cvt_kernel<<<dim3(IMOE / 64, H_DIM / 64, E_NUM), 256, 0, stream>>>(wg, wgT, H_DIM, IMOE);
    transpose_cvt_kernel<<<dim3(IMOE / 64, H_DIM / 64, E_NUM), 256, 0, stream>>>(wu, wuT, H_DIM, IMOE);
    transpose_cvt_kernel<<<dim3(H_DIM / 64, IMOE / 64, E_NUM), 256, 0, stream>>>(wd, wdT, IMOE, H_DIM);
    transpose_cvt_kernel<<<dim3(ISH / 64, H_DIM / 64, 1), 256, 0, stream>>>(shg, shGT, H_DIM, ISH);
    transpose_cvt_kernel<<<dim3(ISH / 64, H_DIM / 64, 1), 256, 0, stream>>>(shu, shUT, H_DIM, ISH);
    transpose_cvt_kernel<<<dim3(H_DIM / 64, ISH / 64, 1), 256, 0, stream>>>(shd, shDT, ISH, H_DIM);

    // routing
    router_kernel<<<N_TOK / 16, 256, 0, stream>>>(h, rw, sgw, topk_idx, topk_w, sg, counts);
    scan_kernel<<<1, 1, 0, stream>>>(counts, offsets, cursor);
    bucketize_kernel<<<N_TOK / 256, 256, 0, stream>>>(topk_idx, cursor, slot_tok, tok_slot);
    gather_kernel<<<SLOTS, 256, 0, stream>>>(h_bf, slot_tok, Agath);

    // routed experts: gate/up fused (N-tile 64), then down
    gemm_dual_kernel<<<dim3(IMOE / 64, N_TOK / MT, E_NUM), 256, 0, stream>>>(
        Agath, wgT, wuT, actR, counts, offsets, H_DIM, IMOE, 0);
    // shared expert gate/up
    gemm_dual_kernel<<<dim3(ISH / 64, N_TOK / MT, 1), 256, 0, stream>>>(
        h_bf, shGT, shUT, actS, nullptr, nullptr, H_DIM, ISH, N_TOK);
    // routed down -> ySlot (raw fp32, slot-major)
    gemm_down_kernel<<<dim3(H_DIM / MT, N_TOK / MT, E_NUM), 256, 0, stream>>>(
        actR, wdT, ySlot, counts, offsets, IMOE, H_DIM, 0);
    // shared down -> ySh (raw fp32; aliases dead actR)
    gemm_down_kernel<<<dim3(H_DIM / MT, N_TOK / MT, 1), 256, 0, stream>>>(
        actS, shDT, ySh, nullptr, nullptr, ISH, H_DIM, N_TOK);
    // final combine: weighted slot rows + sigmoid-gated shared
    combine_kernel<<<N_TOK, 256, 0, stream>>>(ySlot, ySh, tok_slot, topk_w, sg, out);
}

// Round 5
// 1450.867 us; speedup vs baseline: 1.3153x; 1.0057x over previous
//
#include <hip/hip_runtime.h>
#include <stdint.h>

// Qwen3.5 MoE block: N=4096 tokens, H=2048, E=16, K=4, I_moe=1408, I_sh=5632
// R6: L2-grouping orientation fix. The GM=8 m-supertile kept an A-panel of
// 4 MB resident = exactly one XCD L2 -> thrash (FETCH 533 MB vs 63 MB unique
// on shared dual). decode_tile now takes (GS, groupN): group-N keeps a
// GN-ntile B-panel (~2.75 MB) L2-resident and streams A one tile at a time.
// dual: GN=11 group-N (B_total > A_total). down-routed: GM=8 group-M
// (unchanged, already optimal). down-shared: GM=4 group-M (panel 5.6 MB).
// Everything else identical to R5.

#define N_TOK 4096
#define H_DIM 2048
#define E_NUM 16
#define TOPK  4
#define IMOE  1408
#define ISH   5632
#define SLOTS (N_TOK*TOPK)       // 16384

#define MT 128
#define BK 64                     // bf16 elems along k per tile (128 B, 8 chunks)

typedef __attribute__((ext_vector_type(8))) short bf16x8;   // 8 bf16 = 4 VGPRs
typedef __attribute__((ext_vector_type(4))) float f32x4;

static __device__ inline unsigned short f2bf(float f) {
    union { float f; unsigned u; } v; v.f = f;
    unsigned r = v.u + 0x7fffu + ((v.u >> 16) & 1u);   // RNE
    return (unsigned short)(r >> 16);
}

// async global->LDS, 16 bytes per lane. LDS dest = wave-uniform base + lane*16.
static __device__ inline void glds16(const unsigned short* g, unsigned short* l) {
    __builtin_amdgcn_global_load_lds(
        (const __attribute__((address_space(1))) void*)g,
        (__attribute__((address_space(3))) void*)l, 16, 0, 0);
}

// Block-id decode: flat (per-z) id -> (ntile, mtile).
// Step 1: bijective XCD chunking (m204): consecutive logicals stay on one XCD.
// Step 2: L2 supertile. groupN=1: groups of GS ntiles; within a group, nt
// varies fastest and mt sweeps all rows -> the GS B-tiles stay L2-resident
// while A streams one tile at a time (use when B_total > A_total).
// groupN=0: symmetric (GS mtiles resident, B streams).
static __device__ inline bool decode_tile(int bx, int by, int NX, int NYact,
                                          int GS, int groupN, int& nt, int& mt) {
    int f = by * NX + bx;
    int NB = NX * NYact;
    if (f >= NB) return false;
    int q = NB >> 3, rr = NB & 7;
    int x = f & 7, s = f >> 3;
    int L = (x < rr ? x * (q + 1) : rr * (q + 1) + (x - rr) * q) + s;
    if (groupN) {
        int G = GS * NYact;
        int g = L / G, r2 = L - g * G;
        int gn = NX - g * GS; if (gn > GS) gn = GS;
        mt = r2 / gn;
        nt = g * GS + (r2 - mt * gn);
    } else {
        int G = GS * NX;
        int g = L / G, r2 = L - g * G;
        int gm = NYact - g * GS; if (gm > GS) gm = GS;
        nt = r2 / gm;
        mt = g * GS + (r2 - nt * gm);
    }
    return true;
}

// ---------------- fp32 -> bf16 (no transpose), for hidden_states ----------------
__global__ void cvt_h_kernel(const float* __restrict__ in, unsigned short* __restrict__ out, int n4) {
    int i = blockIdx.x * blockDim.x + threadIdx.x;
    if (i < n4) {
        float4 v = *(const float4*)(in + (size_t)i * 4);
        ushort4 o; o.x = f2bf(v.x); o.y = f2bf(v.y); o.z = f2bf(v.z); o.w = f2bf(v.w);
        *(ushort4*)(out + (size_t)i * 4) = o;
    }
}

// ---------------- fp32 [R,C] -> bf16 [C,R] (per z-slice), 64x64 tiles ----------------
__global__ __launch_bounds__(256) void transpose_cvt_kernel(
    const float* __restrict__ in, unsigned short* __restrict__ out, int R, int C) {
    __shared__ float tile[64][65];
    const float* ip = in + (size_t)blockIdx.z * R * C;
    unsigned short* op = out + (size_t)blockIdx.z * R * C;
    int cb = blockIdx.x * 64, rb = blockIdx.y * 64;
    int tid = threadIdx.x;
    int lr = tid >> 4, lc = tid & 15;
#pragma unroll
    for (int p = 0; p < 4; p++) {
        int r = p * 16 + lr;
        float4 v = *(const float4*)(ip + (size_t)(rb + r) * C + cb + lc * 4);
        tile[r][lc * 4 + 0] = v.x;
        tile[r][lc * 4 + 1] = v.y;
        tile[r][lc * 4 + 2] = v.z;
        tile[r][lc * 4 + 3] = v.w;
    }
    __syncthreads();
#pragma unroll
    for (int p = 0; p < 4; p++) {
        int oc = p * 16 + lr;            // output row = source column
        ushort4 o;
        o.x = f2bf(tile[lc * 4 + 0][oc]);
        o.y = f2bf(tile[lc * 4 + 1][oc]);
        o.z = f2bf(tile[lc * 4 + 2][oc]);
        o.w = f2bf(tile[lc * 4 + 3][oc]);
        *(ushort4*)(op + (size_t)(cb + oc) * R + rb + lc * 4) = o;
    }
}

// ---------------- router: 16 tokens/block, float4 loads, shfl reduce ----------------
__global__ __launch_bounds__(256) void router_kernel(
    const float* __restrict__ h, const float* __restrict__ rw, const float* __restrict__ gw,
    int* __restrict__ topk_idx, float* __restrict__ topk_w,
    float* __restrict__ sg, int* __restrict__ counts) {
    int t = threadIdx.x;
    int wv = t >> 6, lane = t & 63;
    int tokw = lane >> 4, part = lane & 15;
    int n = blockIdx.x * 16 + wv * 4 + tokw;
    const float* hp = h + (size_t)n * H_DIM;

    float acc[17];
#pragma unroll
    for (int e = 0; e < 17; e++) acc[e] = 0.f;

    for (int i = 0; i < 32; i++) {
        int j = i * 64 + part * 4;
        float4 hv = *(const float4*)(hp + j);
#pragma unroll
        for (int e = 0; e < E_NUM; e++) {
            float4 w4 = *(const float4*)(rw + (size_t)e * H_DIM + j);
            acc[e] += hv.x * w4.x + hv.y * w4.y + hv.z * w4.z + hv.w * w4.w;
        }
        float4 g4 = *(const float4*)(gw + j);
        acc[16] += hv.x * g4.x + hv.y * g4.y + hv.z * g4.z + hv.w * g4.w;
    }
#pragma unroll
    for (int d = 8; d; d >>= 1)
#pragma unroll
        for (int e = 0; e < 17; e++)
            acc[e] += __shfl_down(acc[e], d, 16);

    if (part == 0) {
        float m = acc[0];
#pragma unroll
        for (int i = 1; i < E_NUM; i++) m = fmaxf(m, acc[i]);
        float p[E_NUM]; float s = 0.f;
#pragma unroll
        for (int i = 0; i < E_NUM; i++) { p[i] = expf(acc[i] - m); s += p[i]; }
        float invs = 1.f / s;
#pragma unroll
        for (int i = 0; i < E_NUM; i++) p[i] *= invs;
        int idx[TOPK]; float val[TOPK]; float vs = 0.f; unsigned used = 0;
#pragma unroll
        for (int k = 0; k < TOPK; k++) {
            int bi = 0; float bv = -1.f;
#pragma unroll
            for (int i = 0; i < E_NUM; i++)
                if (!((used >> i) & 1u) && p[i] > bv) { bv = p[i]; bi = i; }
            idx[k] = bi; val[k] = bv; vs += bv; used |= (1u << bi);
        }
        float inv = 1.f / fmaxf(vs, 1e-9f);
#pragma unroll
        for (int k = 0; k < TOPK; k++) {
            topk_idx[n * TOPK + k] = idx[k];
            topk_w[n * TOPK + k] = val[k] * inv;
            atomicAdd(&counts[idx[k]], 1);
        }
        sg[n] = 1.f / (1.f + expf(-acc[16]));
    }
}

// ---------------- exclusive scan of 16 counts (tiny) ----------------
__global__ void scan_kernel(const int* __restrict__ counts, int* __restrict__ offsets,
                            int* __restrict__ cursor) {
    int s = 0;
    for (int e = 0; e < E_NUM; e++) { offsets[e] = s; cursor[e] = s; s += counts[e]; }
}

// ---------------- scatter token->slot (+ inverse map token->slot ids) ----------------
__global__ void bucketize_kernel(const int* __restrict__ topk_idx,
                                 int* __restrict__ cursor, int* __restrict__ slot_tok,
                                 int* __restrict__ tok_slot) {
    int n = blockIdx.x * blockDim.x + threadIdx.x;
    if (n >= N_TOK) return;
    for (int k = 0; k < TOPK; k++) {
        int e = topk_idx[n * TOPK + k];
        int s = atomicAdd(&cursor[e], 1);
        slot_tok[s] = n;
        tok_slot[n * TOPK + k] = s;
    }
}

// ---------------- gather bf16 token rows into slot order ----------------
__global__ __launch_bounds__(256) void gather_kernel(const unsigned short* __restrict__ hbf,
                                                     const int* __restrict__ slot_tok,
                                                     unsigned short* __restrict__ A) {
    int s = blockIdx.x;
    int tok = slot_tok[s];
    const uint4* src = (const uint4*)(hbf + (size_t)tok * H_DIM);
    uint4* dst = (uint4*)(A + (size_t)s * H_DIM);
    dst[threadIdx.x] = src[threadIdx.x];
}

// ---------------- fused gate/up GEMM + SiLU*mul -> bf16 act ----------------
__global__ __launch_bounds__(256, 2) void gemm_dual_kernel(
    const unsigned short* __restrict__ A, const unsigned short* __restrict__ Bg,
    const unsigned short* __restrict__ Bu, unsigned short* __restrict__ act,
    const int* __restrict__ counts, const int* __restrict__ offsets,
    int K, int N, int fixedM, int GS, int groupN) {
    int e = blockIdx.z;
    int c, off;
    if (counts) { c = counts[e]; off = offsets[e]; } else { c = fixedM; off = 0; }
    int NYact = (c + MT - 1) / MT;
    int nt, mt;
    if (!decode_tile(blockIdx.x, blockIdx.y, gridDim.x, NYact, GS, groupN, nt, mt)) return;

    const unsigned short* Ab = A + (size_t)off * K;
    const unsigned short* Bgb = Bg + (size_t)e * (size_t)N * K;
    const unsigned short* Bub = Bu + (size_t)e * (size_t)N * K;
    unsigned short* actb = act + (size_t)off * N;

    __shared__ __align__(16) unsigned short As[MT * BK];      // 16 KB
    __shared__ __align__(16) unsigned short Bgs[64 * BK];     // 8 KB
    __shared__ __align__(16) unsigned short Bus[64 * BK];     // 8 KB

    int t = threadIdx.x;
    int wave = t >> 6, lane = t & 63;
    int wm = wave >> 1, wn = wave & 1;
    int quad = lane >> 4, l16 = lane & 15;

    f32x4 accg[4][2], accu[4][2];
    for (int i = 0; i < 4; i++) for (int j = 0; j < 2; j++) { accg[i][j] = (f32x4)0.f; accu[i][j] = (f32x4)0.f; }

    int m0 = mt * MT, n0 = nt * 64;
    int rA[4], cA[4];
    for (int j = 0; j < 4; j++) { int s = t + 256 * j; rA[j] = s >> 3; cA[j] = (s & 7) ^ (rA[j] & 7); }
    int rB[2], cB[2];
    for (int j = 0; j < 2; j++) { int s = t + 256 * j; rB[j] = s >> 3; cB[j] = (s & 7) ^ (rB[j] & 7); }

    for (int kt = 0; kt < K; kt += BK) {
        __syncthreads();
        for (int j = 0; j < 4; j++)
            glds16(&Ab[(size_t)(m0 + rA[j]) * K + kt + cA[j] * 8], &As[(t + 256 * j) * 8]);
        for (int j = 0; j < 2; j++) {
            glds16(&Bgb[(size_t)(n0 + rB[j]) * K + kt + cB[j] * 8], &Bgs[(t + 256 * j) * 8]);
            glds16(&Bub[(size_t)(n0 + rB[j]) * K + kt + cB[j] * 8], &Bus[(t + 256 * j) * 8]);
        }
        __syncthreads();
#pragma unroll
        for (int ks = 0; ks < 2; ks++) {
            int lbase = (ks << 2) | quad;
            bf16x8 af[4], bgf[2], buf[2];
            for (int mi = 0; mi < 4; mi++) {
                int rowl = wm * 64 + mi * 16 + l16;
                af[mi] = *(const bf16x8*)&As[rowl * BK + ((lbase ^ (rowl & 7)) * 8)];
            }
            for (int ni = 0; ni < 2; ni++) {
                int rowl = wn * 32 + ni * 16 + l16;
                int co = (lbase ^ (rowl & 7)) * 8;
                bgf[ni] = *(const bf16x8*)&Bgs[rowl * BK + co];
                buf[ni] = *(const bf16x8*)&Bus[rowl * BK + co];
            }
            for (int mi = 0; mi < 4; mi++)
                for (int ni = 0; ni < 2; ni++) {
                    accg[mi][ni] = __builtin_amdgcn_mfma_f32_16x16x32_bf16(af[mi], bgf[ni], accg[mi][ni], 0, 0, 0);
                    accu[mi][ni] = __builtin_amdgcn_mfma_f32_16x16x32_bf16(af[mi], buf[ni], accu[mi][ni], 0, 0, 0);
                }
        }
    }
    for (int mi = 0; mi < 4; mi++) {
        for (int r = 0; r < 4; r++) {
            int rl = m0 + wm * 64 + mi * 16 + quad * 4 + r;
            if (rl < c) {
                size_t rowbase = (size_t)rl * N + n0 + wn * 32 + l16;
                for (int ni = 0; ni < 2; ni++) {
                    float g = accg[mi][ni][r];
                    float u = accu[mi][ni][r];
                    float a = (g / (1.f + __expf(-g))) * u;
                    actb[rowbase + ni * 16] = f2bf(a);
                }
            }
        }
    }
}

// ---------------- down GEMM -> raw fp32 rows (no atomics, no scaling) ----------------
__global__ __launch_bounds__(256, 2) void gemm_down_kernel(
    const unsigned short* __restrict__ Aact, const unsigned short* __restrict__ Bd,
    float* __restrict__ Y,
    const int* __restrict__ counts, const int* __restrict__ offsets,
    int K, int N, int fixedM, int GS, int groupN) {
    int e = blockIdx.z;
    int c, off;
    if (counts) { c = counts[e]; off = offsets[e]; } else { c = fixedM; off = 0; }
    int NYact = (c + MT - 1) / MT;
    int nt, mt;
    if (!decode_tile(blockIdx.x, blockIdx.y, gridDim.x, NYact, GS, groupN, nt, mt)) return;

    const unsigned short* Ab = Aact + (size_t)off * K;
    const unsigned short* Bb = Bd + (size_t)e * (size_t)N * K;

    __shared__ __align__(16) unsigned short As[MT * BK];      // 16 KB
    __shared__ __align__(16) unsigned short Bs[MT * BK];      // 16 KB

    int t = threadIdx.x;
    int wave = t >> 6, lane = t & 63;
    int wm = wave >> 1, wn = wave & 1;
    int quad = lane >> 4, l16 = lane & 15;

    f32x4 acc[4][4];
    for (int i = 0; i < 4; i++) for (int j = 0; j < 4; j++) acc[i][j] = (f32x4)0.f;

    int m0 = mt * MT, n0 = nt * MT;
    int rA[4], cA[4];
    for (int j = 0; j < 4; j++) { int s = t + 256 * j; rA[j] = s >> 3; cA[j] = (s & 7) ^ (rA[j] & 7); }

    for (int kt = 0; kt < K; kt += BK) {
        __syncthreads();
        for (int j = 0; j < 4; j++) {
            glds16(&Ab[(size_t)(m0 + rA[j]) * K + kt + cA[j] * 8], &As[(t + 256 * j) * 8]);
            glds16(&Bb[(size_t)(n0 + rA[j]) * K + kt + cA[j] * 8], &Bs[(t + 256 * j) * 8]);
        }
        __syncthreads();
#pragma unroll
        for (int ks = 0; ks < 2; ks++) {
            int lbase = (ks << 2) | quad;
            bf16x8 af[4], bf[4];
            for (int mi = 0; mi < 4; mi++) {
                int rowl = wm * 64 + mi * 16 + l16;
                af[mi] = *(const bf16x8*)&As[rowl * BK + ((lbase ^ (rowl & 7)) * 8)];
            }
            for (int ni = 0; ni < 4; ni++) {
                int rowl = wn * 64 + ni * 16 + l16;
                bf[ni] = *(const bf16x8*)&Bs[rowl * BK + ((lbase ^ (rowl & 7)) * 8)];
            }
            for (int mi = 0; mi < 4; mi++)
                for (int ni = 0; ni < 4; ni++)
                    acc[mi][ni] = __builtin_amdgcn_mfma_f32_16x16x32_bf16(af[mi], bf[ni], acc[mi][ni], 0, 0, 0);
        }
    }
    for (int mi = 0; mi < 4; mi++) {
        for (int r = 0; r < 4; r++) {
            int rl = m0 + wm * 64 + mi * 16 + quad * 4 + r;
            if (rl < c) {
                int col = n0 + wn * 64 + l16;
                float* ob = Y + (size_t)(off + rl) * N + col;
                for (int ni = 0; ni < 4; ni++)
                    ob[ni * 16] = acc[mi][ni][r];
            }
        }
    }
}

// ---------------- combine: out[n] = sum_k w_k * ySlot[slot(n,k)] + sg[n] * ySh[n] ----------------
__global__ __launch_bounds__(256) void combine_kernel(
    const float* __restrict__ ySlot, const float* __restrict__ ySh,
    const int* __restrict__ tok_slot, const float* __restrict__ topk_w,
    const float* __restrict__ sgv, float* __restrict__ out) {
    int n = blockIdx.x;
    int s0 = tok_slot[n * TOPK + 0], s1 = tok_slot[n * TOPK + 1];
    int s2 = tok_slot[n * TOPK + 2], s3 = tok_slot[n * TOPK + 3];
    float w0 = topk_w[n * TOPK + 0], w1 = topk_w[n * TOPK + 1];
    float w2 = topk_w[n * TOPK + 2], w3 = topk_w[n * TOPK + 3];
    float g = sgv[n];
    const float4* p0 = (const float4*)(ySlot + (size_t)s0 * H_DIM);
    const float4* p1 = (const float4*)(ySlot + (size_t)s1 * H_DIM);
    const float4* p2 = (const float4*)(ySlot + (size_t)s2 * H_DIM);
    const float4* p3 = (const float4*)(ySlot + (size_t)s3 * H_DIM);
    const float4* ps = (const float4*)(ySh + (size_t)n * H_DIM);
    float4* po = (float4*)(out + (size_t)n * H_DIM);
#pragma unroll
    for (int it = 0; it < H_DIM / 4 / 256; it++) {
        int i = it * 256 + threadIdx.x;
        float4 a = p0[i], b = p1[i], cc = p2[i], d = p3[i], s = ps[i];
        float4 r;
        r.x = w0 * a.x + w1 * b.x + w2 * cc.x + w3 * d.x + g * s.x;
        r.y = w0 * a.y + w1 * b.y + w2 * cc.y + w3 * d.y + g * s.y;
        r.z = w0 * a.z + w1 * b.z + w2 * cc.z + w3 * d.z + g * s.z;
        r.w = w0 * a.w + w1 * b.w + w2 * cc.w + w3 * d.w + g * s.w;
        po[i] = r;
    }
}

extern "C" void kernel_launch(void* const* d_in, const int* in_sizes, int n_in,
                              void* d_out, int out_size, void* d_ws, size_t ws_size,
                              hipStream_t stream) {
    const float* h   = (const float*)d_in[0];
    const float* rw  = (const float*)d_in[1];
    const float* wg  = (const float*)d_in[2];
    const float* wu  = (const float*)d_in[3];
    const float* wd  = (const float*)d_in[4];
    const float* shg = (const float*)d_in[5];
    const float* shu = (const float*)d_in[6];
    const float* shd = (const float*)d_in[7];
    const float* sgw = (const float*)d_in[8];
    float* out = (float*)d_out;

    char* ws = (char*)d_ws;
    size_t off = 0;
    auto alloc = [&](size_t b) { size_t o = off; off += (b + 255) & ~(size_t)255; return (void*)(ws + o); };

    int*   counts   = (int*)  alloc(E_NUM * 4);
    int*   offsets  = (int*)  alloc(E_NUM * 4);
    int*   cursor   = (int*)  alloc(E_NUM * 4);
    int*   topk_idx = (int*)  alloc((size_t)N_TOK * TOPK * 4);
    float* topk_w   = (float*)alloc((size_t)N_TOK * TOPK * 4);
    float* sg       = (float*)alloc((size_t)N_TOK * 4);
    int*   slot_tok = (int*)  alloc((size_t)SLOTS * 4);
    int*   tok_slot = (int*)  alloc((size_t)SLOTS * 4);
    unsigned short* h_bf  = (unsigned short*)alloc((size_t)N_TOK * H_DIM * 2);
    unsigned short* wgT   = (unsigned short*)alloc((size_t)E_NUM * IMOE * H_DIM * 2);
    unsigned short* wuT   = (unsigned short*)alloc((size_t)E_NUM * IMOE * H_DIM * 2);
    unsigned short* wdT   = (unsigned short*)alloc((size_t)E_NUM * H_DIM * IMOE * 2);
    unsigned short* shGT  = (unsigned short*)alloc((size_t)ISH * H_DIM * 2);
    unsigned short* shUT  = (unsigned short*)alloc((size_t)ISH * H_DIM * 2);
    unsigned short* shDT  = (unsigned short*)alloc((size_t)H_DIM * ISH * 2);
    unsigned short* Agath = (unsigned short*)alloc((size_t)(SLOTS + 2 * MT) * H_DIM * 2);
    unsigned short* actR  = (unsigned short*)alloc((size_t)(SLOTS + 2 * MT) * IMOE * 2);
    unsigned short* actS  = (unsigned short*)alloc((size_t)N_TOK * ISH * 2);
    float* ySlot = (float*)alloc((size_t)SLOTS * H_DIM * 4);
    float* ySh   = (float*)actR;   // actR dead after routed down; 33.5MB <= 46.5MB
    (void)ws_size; (void)in_sizes; (void)n_in; (void)out_size;

    hipMemsetAsync(counts, 0, E_NUM * 4, stream);

    // bf16 conversions
    cvt_h_kernel<<<(N_TOK * H_DIM / 4 + 255) / 256, 256, 0, stream>>>(h, h_bf, N_TOK * H_DIM / 4);
    transpose_cvt_kernel<<<dim3(IMOE / 64, H_DIM / 64, E_NUM), 256, 0, stream>>>(wg, wgT, H_DIM, IMOE);
    transpose_cvt_kernel<<<dim3(IMOE / 64, H_DIM / 64, E_NUM), 256, 0, stream>>>(wu, wuT, H_DIM, IMOE);
    transpose_cvt_kernel<<<dim3(H_DIM / 64, IMOE / 64, E_NUM), 256, 0, stream>>>(wd, wdT, IMOE, H_DIM);
    transpose_cvt_kernel<<<dim3(ISH / 64, H_DIM / 64, 1), 256, 0, stream>>>(shg, shGT, H_DIM, ISH);
    transpose_cvt_kernel<<<dim3(ISH / 64, H_DIM / 64, 1), 256, 0, stream>>>(shu, shUT, H_DIM, ISH);
    transpose_cvt_kernel<<<dim3(H_DIM / 64, ISH / 64, 1), 256, 0, stream>>>(shd, shDT, ISH, H_DIM);

    // routing
    router_kernel<<<N_TOK / 16, 256, 0, stream>>>(h, rw, sgw, topk_idx, topk_w, sg, counts);
    scan_kernel<<<1, 1, 0, stream>>>(counts, offsets, cursor);
    bucketize_kernel<<<N_TOK / 256, 256, 0, stream>>>(topk_idx, cursor, slot_tok, tok_slot);
    gather_kernel<<<SLOTS, 256, 0, stream>>>(h_bf, slot_tok, Agath);

    // routed experts: gate/up fused (N-tile 64), group-N GN=11 (B-panel 2.75MB resident)
    gemm_dual_kernel<<<dim3(IMOE / 64, N_TOK / MT, E_NUM), 256, 0, stream>>>(
        Agath, wgT, wuT, actR, counts, offsets, H_DIM, IMOE, 0, 11, 1);
    // shared expert gate/up: group-N GN=11 (88 ntiles -> 8 groups = 1/XCD)
    gemm_dual_kernel<<<dim3(ISH / 64, N_TOK / MT, 1), 256, 0, stream>>>(
        h_bf, shGT, shUT, actS, nullptr, nullptr, H_DIM, ISH, N_TOK, 11, 1);
    // routed down -> ySlot: group-M GM=8 (A-panel 2.8MB resident, unchanged)
    gemm_down_kernel<<<dim3(H_DIM / MT, N_TOK / MT, E_NUM), 256, 0, stream>>>(
        actR, wdT, ySlot, counts, offsets, IMOE, H_DIM, 0, 8, 0);
    // shared down -> ySh: group-M GM=4 (panel 5.6MB, was 11.5MB thrash)
    gemm_down_kernel<<<dim3(H_DIM / MT, N_TOK / MT, 1), 256, 0, stream>>>(
        actS, shDT, ySh, nullptr, nullptr, ISH, H_DIM, N_TOK, 4, 0);
    // final combine: weighted slot rows + sigmoid-gated shared
    combine_kernel<<<N_TOK, 256, 0, stream>>>(ySlot, ySh, tok_slot, topk_w, sg, out);
}